// Round 1
// baseline (5748.362 us; speedup 1.0000x reference)
//
#include <hip/hip_runtime.h>
#include <hip/hip_bf16.h>

#define H 128
#define NH4(n) ((size_t)(n) * H * sizeof(float))

// ---------------------------------------------------------------------------
// prep: combined weights  wc = wA + wB  and biases bc = bl + bA + bB
// ---------------------------------------------------------------------------
__global__ void prep_weights(const float* __restrict__ w01, const float* __restrict__ w11,
                             const float* __restrict__ bl1, const float* __restrict__ b01,
                             const float* __restrict__ b11,
                             const float* __restrict__ w00, const float* __restrict__ w10,
                             const float* __restrict__ bl0, const float* __restrict__ b00,
                             const float* __restrict__ b10,
                             float* __restrict__ wc1, float* __restrict__ bc1,
                             float* __restrict__ wc0, float* __restrict__ bc0) {
    int i = blockIdx.x * 256 + threadIdx.x;
    if (i < H * H) {
        wc1[i] = w01[i] + w11[i];
        wc0[i] = w00[i] + w10[i];
    }
    if (i < H) {
        bc1[i] = bl1[i] + b01[i] + b11[i];
        bc0[i] = bl0[i] + b00[i] + b10[i];
    }
}

// ---------------------------------------------------------------------------
// scatter: agg[edge0[e]] += h[edge1[e]]   (one thread per (edge, 4 floats))
// ---------------------------------------------------------------------------
__global__ __launch_bounds__(256) void scatter_add(const float* __restrict__ h,
                                                   const int* __restrict__ edge,
                                                   int E, float* __restrict__ agg) {
    unsigned tid = blockIdx.x * 256u + threadIdx.x;
    unsigned e = tid >> 5;
    if (e >= (unsigned)E) return;
    int q = (tid & 31) << 2;           // float offset within row: 0,4,...,124
    int dst = edge[e];                 // edge[0][e]
    int src = edge[E + e];             // edge[1][e]
    const float4 v = *(const float4*)(h + (size_t)src * H + q);
    float* p = agg + (size_t)dst * H + q;
    atomicAdd(p + 0, v.x);
    atomicAdd(p + 1, v.y);
    atomicAdd(p + 2, v.z);
    atomicAdd(p + 3, v.w);
}

// ---------------------------------------------------------------------------
// fused GEMM:  out = [relu]( A @ W1 [+ B @ W2] + bias )   rows tiled by 32
// Safe for out == A (block reads only its own 32 rows into LDS first).
// ---------------------------------------------------------------------------
template <int TWO, int RELU>
__global__ __launch_bounds__(256) void gemm_tile(const float* __restrict__ A,
                                                 const float* __restrict__ B,
                                                 const float* __restrict__ W1,
                                                 const float* __restrict__ W2,
                                                 const float* __restrict__ bias,
                                                 float* __restrict__ out, int nrows) {
    __shared__ float As[32][H];
    __shared__ float Bs[32][H];
    int row0 = blockIdx.x * 32;
    int tid = threadIdx.x;

    {
        const float4* Ap = (const float4*)(A + (size_t)row0 * H);
        float4* As4 = (float4*)&As[0][0];
        #pragma unroll
        for (int i = 0; i < 4; ++i) As4[tid + 256 * i] = Ap[tid + 256 * i];
        if (TWO) {
            const float4* Bp = (const float4*)(B + (size_t)row0 * H);
            float4* Bs4 = (float4*)&Bs[0][0];
            #pragma unroll
            for (int i = 0; i < 4; ++i) Bs4[tid + 256 * i] = Bp[tid + 256 * i];
        }
    }
    __syncthreads();

    int c4 = tid & 31;   // column group: cols c4*4 .. c4*4+3
    int rg = tid >> 5;   // row group: rows rg*4 .. rg*4+3
    float4 bv = *(const float4*)(bias + c4 * 4);
    float4 acc[4] = {bv, bv, bv, bv};

    const float4* W1p = (const float4*)W1;
    const float4* W2p = (const float4*)W2;

    for (int k = 0; k < H; ++k) {
        float4 w1 = W1p[k * 32 + c4];
        #pragma unroll
        for (int i = 0; i < 4; ++i) {
            float a = As[rg * 4 + i][k];
            acc[i].x += a * w1.x;
            acc[i].y += a * w1.y;
            acc[i].z += a * w1.z;
            acc[i].w += a * w1.w;
        }
        if (TWO) {
            float4 w2 = W2p[k * 32 + c4];
            #pragma unroll
            for (int i = 0; i < 4; ++i) {
                float b = Bs[rg * 4 + i][k];
                acc[i].x += b * w2.x;
                acc[i].y += b * w2.y;
                acc[i].z += b * w2.z;
                acc[i].w += b * w2.w;
            }
        }
    }

    #pragma unroll
    for (int i = 0; i < 4; ++i) {
        int r = row0 + rg * 4 + i;
        if (r < nrows) {
            float4 o = acc[i];
            if (RELU) {
                o.x = fmaxf(o.x, 0.f);
                o.y = fmaxf(o.y, 0.f);
                o.z = fmaxf(o.z, 0.f);
                o.w = fmaxf(o.w, 0.f);
            }
            *(float4*)(out + (size_t)r * H + c4 * 4) = o;
        }
    }
}

extern "C" void kernel_launch(void* const* d_in, const int* in_sizes, int n_in,
                              void* d_out, int out_size, void* d_ws, size_t ws_size,
                              hipStream_t stream) {
    const float* x_A  = (const float*)d_in[0];
    // d_in[1] = x_B  (unused by the math)
    const int* edge_r0 = (const int*)d_in[2];
    const int* edge_r1 = (const int*)d_in[3];
    const float* wl0 = (const float*)d_in[4];
    const float* bl0 = (const float*)d_in[5];
    const float* w00 = (const float*)d_in[6];
    const float* b00 = (const float*)d_in[7];
    const float* w10 = (const float*)d_in[8];
    const float* b10 = (const float*)d_in[9];
    const float* wl1 = (const float*)d_in[10];
    const float* bl1 = (const float*)d_in[11];
    const float* w01 = (const float*)d_in[12];
    const float* b01 = (const float*)d_in[13];
    const float* w11 = (const float*)d_in[14];
    const float* b11 = (const float*)d_in[15];
    const float* w_out = (const float*)d_in[16];
    const float* b_out = (const float*)d_in[17];

    const int N = in_sizes[0] / H;          // 100000
    const int E = in_sizes[2] / 2;          // 1600000

    char* ws = (char*)d_ws;
    float* agg = (float*)ws;                         // N*H floats
    float* h1  = (float*)(ws + NH4(N));              // N*H floats
    float* wc1 = (float*)(ws + 2 * NH4(N));          // H*H
    float* wc0 = wc1 + H * H;                        // H*H
    float* bc1 = wc0 + H * H;                        // H
    float* bc0 = bc1 + H;                            // H
    float* h2  = (float*)d_out;                      // reuse output as h2

    // combined weights
    prep_weights<<<(H * H + 255) / 256, 256, 0, stream>>>(
        w01, w11, bl1, b01, b11, w00, w10, bl0, b00, b10, wc1, bc1, wc0, bc0);

    const int scatterBlocks = (E * 32 + 255) / 256;
    const int gemmBlocks = (N + 31) / 32;

    // ---- layer 1: edge_r1, wl1, wc1, bc1 : x_A -> h1 ----
    hipMemsetAsync(agg, 0, NH4(N), stream);
    scatter_add<<<scatterBlocks, 256, 0, stream>>>(x_A, edge_r1, E, agg);
    gemm_tile<1, 1><<<gemmBlocks, 256, 0, stream>>>(agg, x_A, wl1, wc1, bc1, h1, N);

    // ---- layer 2: edge_r0, wl0, wc0, bc0 : h1 -> h2 (stored in d_out) ----
    hipMemsetAsync(agg, 0, NH4(N), stream);
    scatter_add<<<scatterBlocks, 256, 0, stream>>>(h1, edge_r0, E, agg);
    gemm_tile<1, 1><<<gemmBlocks, 256, 0, stream>>>(agg, h1, wl0, wc0, bc0, h2, N);

    // ---- out = h2 @ w_out + b_out  (in-place on d_out; row-tile safe) ----
    gemm_tile<0, 0><<<gemmBlocks, 256, 0, stream>>>(h2, nullptr, w_out, nullptr, b_out, h2, N);
}

// Round 2
// 1441.929 us; speedup vs baseline: 3.9866x; 3.9866x over previous
//
#include <hip/hip_runtime.h>
#include <hip/hip_bf16.h>

#define H 128

// ---------------------------------------------------------------------------
// prep: combined weights  wc = w0 + w1  and biases bc = bl + b0 + b1
// ---------------------------------------------------------------------------
__global__ void prep_weights(const float* __restrict__ w01, const float* __restrict__ w11,
                             const float* __restrict__ bl1, const float* __restrict__ b01,
                             const float* __restrict__ b11,
                             const float* __restrict__ w00, const float* __restrict__ w10,
                             const float* __restrict__ bl0, const float* __restrict__ b00,
                             const float* __restrict__ b10,
                             float* __restrict__ wc1, float* __restrict__ bc1,
                             float* __restrict__ wc0, float* __restrict__ bc0) {
    int i = blockIdx.x * 256 + threadIdx.x;
    if (i < H * H) {
        wc1[i] = w01[i] + w11[i];
        wc0[i] = w00[i] + w10[i];
    }
    if (i < H) {
        bc1[i] = bl1[i] + b01[i] + b11[i];
        bc0[i] = bl0[i] + b00[i] + b10[i];
    }
}

// ---------------------------------------------------------------------------
// CSR build: histogram -> scan -> fill
// ---------------------------------------------------------------------------
__global__ __launch_bounds__(256) void csr_hist(const int* __restrict__ edge, int E,
                                                int* __restrict__ counts) {
    int i = blockIdx.x * 256 + threadIdx.x;
    if (i < E) atomicAdd(&counts[edge[i]], 1);   // edge[0][i] = dst
}

__global__ __launch_bounds__(1024) void csr_scan(const int* __restrict__ counts, int n,
                                                 int* __restrict__ row_ptr,
                                                 int* __restrict__ cursor) {
    __shared__ int buf[1024];
    int tid = threadIdx.x;
    int chunk = (n + 1023) >> 10;
    int lo = tid * chunk;
    int hi = min(lo + chunk, n);
    int s = 0;
    for (int i = lo; i < hi; ++i) s += counts[i];
    buf[tid] = s;
    __syncthreads();
    for (int d = 1; d < 1024; d <<= 1) {
        int v = (tid >= d) ? buf[tid - d] : 0;
        __syncthreads();
        buf[tid] += v;
        __syncthreads();
    }
    int off = buf[tid] - s;                      // exclusive prefix
    for (int i = lo; i < hi; ++i) {
        row_ptr[i] = off;
        cursor[i] = off;
        off += counts[i];
    }
    if (tid == 1023) row_ptr[n] = off;           // total (tid 1023's range is past n)
}

__global__ __launch_bounds__(256) void csr_fill(const int* __restrict__ edge, int E,
                                                int* __restrict__ cursor,
                                                int* __restrict__ col) {
    int i = blockIdx.x * 256 + threadIdx.x;
    if (i >= E) return;
    int dst = edge[i];
    int src = edge[E + i];
    int pos = atomicAdd(&cursor[dst], 1);
    col[pos] = src;
}

// ---------------------------------------------------------------------------
// gather: U[i] = relu( U[i] + sum_{src in adj(i)} T[src] )   (in-place on U)
// one 32-lane group per node; lane owns float4 (4 cols)
// ---------------------------------------------------------------------------
__global__ __launch_bounds__(256) void gather_relu(const float* __restrict__ T,
                                                   const int* __restrict__ row_ptr,
                                                   const int* __restrict__ col,
                                                   float* __restrict__ U, int n) {
    int g = (int)((blockIdx.x * 256u + threadIdx.x) >> 5);
    int lane = threadIdx.x & 31;
    if (g >= n) return;
    int start = row_ptr[g];
    int end = row_ptr[g + 1];
    float4 acc = *(const float4*)(U + (size_t)g * H + lane * 4);
    for (int e0 = start; e0 < end; e0 += 32) {
        int idx = e0 + lane;
        int myc = (idx < end) ? col[idx] : 0;
        int cnt = min(32, end - e0);
        for (int j = 0; j < cnt; ++j) {
            int src = __shfl(myc, j, 32);
            const float4 v = *(const float4*)(T + (size_t)src * H + lane * 4);
            acc.x += v.x; acc.y += v.y; acc.z += v.z; acc.w += v.w;
        }
    }
    acc.x = fmaxf(acc.x, 0.f);
    acc.y = fmaxf(acc.y, 0.f);
    acc.z = fmaxf(acc.z, 0.f);
    acc.w = fmaxf(acc.w, 0.f);
    *(float4*)(U + (size_t)g * H + lane * 4) = acc;
}

// ---------------------------------------------------------------------------
// dual GEMM: T = A@W1 ; U = A@W2 + bias   (rows tiled by 32; safe for U==A)
// ---------------------------------------------------------------------------
__global__ __launch_bounds__(256) void gemm_dual(const float* __restrict__ A,
                                                 const float* __restrict__ W1,
                                                 const float* __restrict__ W2,
                                                 const float* __restrict__ bias,
                                                 float* __restrict__ T,
                                                 float* __restrict__ U, int nrows) {
    __shared__ float As[32][H];
    int row0 = blockIdx.x * 32;
    int tid = threadIdx.x;
    {
        const float4* Ap = (const float4*)(A + (size_t)row0 * H);
        float4* As4 = (float4*)&As[0][0];
        #pragma unroll
        for (int i = 0; i < 4; ++i) As4[tid + 256 * i] = Ap[tid + 256 * i];
    }
    __syncthreads();

    int c4 = tid & 31;
    int rg = tid >> 5;
    float4 bv = *(const float4*)(bias + c4 * 4);
    float4 acc1[4] = {{0,0,0,0},{0,0,0,0},{0,0,0,0},{0,0,0,0}};
    float4 acc2[4] = {bv, bv, bv, bv};

    const float4* W1p = (const float4*)W1;
    const float4* W2p = (const float4*)W2;

    for (int k = 0; k < H; ++k) {
        float4 w1 = W1p[k * 32 + c4];
        float4 w2 = W2p[k * 32 + c4];
        #pragma unroll
        for (int i = 0; i < 4; ++i) {
            float a = As[rg * 4 + i][k];
            acc1[i].x += a * w1.x; acc1[i].y += a * w1.y;
            acc1[i].z += a * w1.z; acc1[i].w += a * w1.w;
            acc2[i].x += a * w2.x; acc2[i].y += a * w2.y;
            acc2[i].z += a * w2.z; acc2[i].w += a * w2.w;
        }
    }

    #pragma unroll
    for (int i = 0; i < 4; ++i) {
        int r = row0 + rg * 4 + i;
        if (r < nrows) {
            *(float4*)(T + (size_t)r * H + c4 * 4) = acc1[i];
            *(float4*)(U + (size_t)r * H + c4 * 4) = acc2[i];
        }
    }
}

// ---------------------------------------------------------------------------
// single GEMM: out = A@W + bias   (no relu)
// ---------------------------------------------------------------------------
__global__ __launch_bounds__(256) void gemm_single(const float* __restrict__ A,
                                                   const float* __restrict__ W,
                                                   const float* __restrict__ bias,
                                                   float* __restrict__ out, int nrows) {
    __shared__ float As[32][H];
    int row0 = blockIdx.x * 32;
    int tid = threadIdx.x;
    {
        const float4* Ap = (const float4*)(A + (size_t)row0 * H);
        float4* As4 = (float4*)&As[0][0];
        #pragma unroll
        for (int i = 0; i < 4; ++i) As4[tid + 256 * i] = Ap[tid + 256 * i];
    }
    __syncthreads();

    int c4 = tid & 31;
    int rg = tid >> 5;
    float4 bv = *(const float4*)(bias + c4 * 4);
    float4 acc[4] = {bv, bv, bv, bv};
    const float4* Wp = (const float4*)W;

    for (int k = 0; k < H; ++k) {
        float4 w = Wp[k * 32 + c4];
        #pragma unroll
        for (int i = 0; i < 4; ++i) {
            float a = As[rg * 4 + i][k];
            acc[i].x += a * w.x; acc[i].y += a * w.y;
            acc[i].z += a * w.z; acc[i].w += a * w.w;
        }
    }
    #pragma unroll
    for (int i = 0; i < 4; ++i) {
        int r = row0 + rg * 4 + i;
        if (r < nrows)
            *(float4*)(out + (size_t)r * H + c4 * 4) = acc[i];
    }
}

extern "C" void kernel_launch(void* const* d_in, const int* in_sizes, int n_in,
                              void* d_out, int out_size, void* d_ws, size_t ws_size,
                              hipStream_t stream) {
    const float* x_A  = (const float*)d_in[0];
    const int* edge_r0 = (const int*)d_in[2];
    const int* edge_r1 = (const int*)d_in[3];
    const float* wl0 = (const float*)d_in[4];
    const float* bl0 = (const float*)d_in[5];
    const float* w00 = (const float*)d_in[6];
    const float* b00 = (const float*)d_in[7];
    const float* w10 = (const float*)d_in[8];
    const float* b10 = (const float*)d_in[9];
    const float* wl1 = (const float*)d_in[10];
    const float* bl1 = (const float*)d_in[11];
    const float* w01 = (const float*)d_in[12];
    const float* b01 = (const float*)d_in[13];
    const float* w11 = (const float*)d_in[14];
    const float* b11 = (const float*)d_in[15];
    const float* w_out = (const float*)d_in[16];
    const float* b_out = (const float*)d_in[17];

    const int N = in_sizes[0] / H;       // 100000
    const int E = in_sizes[2] / 2;       // 1600000

    char* ws = (char*)d_ws;
    float* U       = (float*)ws;                         ws += (size_t)N * H * sizeof(float);
    int*   row_ptr = (int*)ws;                           ws += (size_t)(N + 1) * sizeof(int);
    int*   cursor  = (int*)ws;                           ws += (size_t)N * sizeof(int);
    int*   counts  = (int*)ws;                           ws += (size_t)N * sizeof(int);
    int*   colbuf  = (int*)ws;                           ws += (size_t)E * sizeof(int);
    float* wc1     = (float*)ws;                         ws += H * H * sizeof(float);
    float* wc0     = (float*)ws;                         ws += H * H * sizeof(float);
    float* bc1     = (float*)ws;                         ws += H * sizeof(float);
    float* bc0     = (float*)ws;                         ws += H * sizeof(float);
    float* T       = (float*)d_out;   // t-buffer lives in d_out until the end

    prep_weights<<<(H * H + 255) / 256, 256, 0, stream>>>(
        w01, w11, bl1, b01, b11, w00, w10, bl0, b00, b10, wc1, bc1, wc0, bc0);

    const int eBlocks = (E + 255) / 256;
    const int gemmBlocks = (N + 31) / 32;
    const int gatherBlocks = (N * 32 + 255) / 256;

    // ---- layer 1 (edge_r1): t1 = x_A@wl1 -> T ; u1 = x_A@wc1+bc1 -> U ----
    hipMemsetAsync(counts, 0, (size_t)N * sizeof(int), stream);
    csr_hist<<<eBlocks, 256, 0, stream>>>(edge_r1, E, counts);
    csr_scan<<<1, 1024, 0, stream>>>(counts, N, row_ptr, cursor);
    csr_fill<<<eBlocks, 256, 0, stream>>>(edge_r1, E, cursor, colbuf);
    gemm_dual<<<gemmBlocks, 256, 0, stream>>>(x_A, wl1, wc1, bc1, T, U, N);
    gather_relu<<<gatherBlocks, 256, 0, stream>>>(T, row_ptr, colbuf, U, N);  // h1 = U

    // ---- layer 2 (edge_r0): t2 = h1@wl0 -> T ; u2 = h1@wc0+bc0 -> U (in-place) ----
    hipMemsetAsync(counts, 0, (size_t)N * sizeof(int), stream);
    csr_hist<<<eBlocks, 256, 0, stream>>>(edge_r0, E, counts);
    csr_scan<<<1, 1024, 0, stream>>>(counts, N, row_ptr, cursor);
    csr_fill<<<eBlocks, 256, 0, stream>>>(edge_r0, E, cursor, colbuf);
    gemm_dual<<<gemmBlocks, 256, 0, stream>>>(U, wl0, wc0, bc0, T, U, N);
    gather_relu<<<gatherBlocks, 256, 0, stream>>>(T, row_ptr, colbuf, U, N);  // h2 = U

    // ---- out = h2 @ w_out + b_out  (reads U, writes d_out; no aliasing) ----
    gemm_single<<<gemmBlocks, 256, 0, stream>>>(U, w_out, b_out, (float*)d_out, N);
}

// Round 3
// 996.684 us; speedup vs baseline: 5.7675x; 1.4467x over previous
//
#include <hip/hip_runtime.h>
#include <hip/hip_bf16.h>

#define H 128

// ---------------------------------------------------------------------------
// prep: combined weights  wc = w0 + w1  and biases bc = bl + b0 + b1
// ---------------------------------------------------------------------------
__global__ void prep_weights(const float* __restrict__ w01, const float* __restrict__ w11,
                             const float* __restrict__ bl1, const float* __restrict__ b01,
                             const float* __restrict__ b11,
                             const float* __restrict__ w00, const float* __restrict__ w10,
                             const float* __restrict__ bl0, const float* __restrict__ b00,
                             const float* __restrict__ b10,
                             float* __restrict__ wc1, float* __restrict__ bc1,
                             float* __restrict__ wc0, float* __restrict__ bc0) {
    int i = blockIdx.x * 256 + threadIdx.x;
    if (i < H * H) {
        wc1[i] = w01[i] + w11[i];
        wc0[i] = w00[i] + w10[i];
    }
    if (i < H) {
        bc1[i] = bl1[i] + b01[i] + b11[i];
        bc0[i] = bl0[i] + b00[i] + b10[i];
    }
}

// ---------------------------------------------------------------------------
// CSR build: histogram -> hierarchical scan (blocksum/scanpart/writeptr) -> fill
// ---------------------------------------------------------------------------
__global__ __launch_bounds__(256) void csr_hist(const int* __restrict__ edge, int E,
                                                int* __restrict__ counts) {
    int i = blockIdx.x * 256 + threadIdx.x;
    if (i < E) atomicAdd(&counts[edge[i]], 1);   // edge[0][i] = dst
}

// stage 1: partials[b] = sum of counts[b*1024 .. b*1024+1023]
__global__ __launch_bounds__(256) void csr_blocksum(const int* __restrict__ counts, int n,
                                                    int* __restrict__ partials) {
    __shared__ int red[256];
    int tid = threadIdx.x;
    int idx = blockIdx.x * 1024 + tid * 4;
    int s = 0;
    if (idx + 3 < n) {
        int4 c = *(const int4*)(counts + idx);
        s = c.x + c.y + c.z + c.w;
    } else {
        for (int j = 0; j < 4; ++j)
            if (idx + j < n) s += counts[idx + j];
    }
    red[tid] = s;
    __syncthreads();
    for (int d = 128; d > 0; d >>= 1) {
        if (tid < d) red[tid] += red[tid + d];
        __syncthreads();
    }
    if (tid == 0) partials[blockIdx.x] = red[0];
}

// stage 2: exclusive scan of partials (nb <= 256), in place
__global__ __launch_bounds__(256) void csr_scanpart(int* __restrict__ partials, int nb) {
    __shared__ int buf[256];
    int tid = threadIdx.x;
    int v = (tid < nb) ? partials[tid] : 0;
    buf[tid] = v;
    __syncthreads();
    for (int d = 1; d < 256; d <<= 1) {
        int t = (tid >= d) ? buf[tid - d] : 0;
        __syncthreads();
        buf[tid] += t;
        __syncthreads();
    }
    if (tid < nb) partials[tid] = buf[tid] - v;   // exclusive prefix
}

// stage 3: row_ptr/cursor from block-local exclusive scan + partial offset
__global__ __launch_bounds__(256) void csr_writeptr(const int* __restrict__ counts, int n,
                                                    const int* __restrict__ partials,
                                                    int* __restrict__ row_ptr,
                                                    int* __restrict__ cursor, int E) {
    __shared__ int red[256];
    int tid = threadIdx.x;
    int idx = blockIdx.x * 1024 + tid * 4;
    int4 c = {0, 0, 0, 0};
    if (idx + 3 < n) {
        c = *(const int4*)(counts + idx);
    } else {
        if (idx + 0 < n) c.x = counts[idx + 0];
        if (idx + 1 < n) c.y = counts[idx + 1];
        if (idx + 2 < n) c.z = counts[idx + 2];
    }
    int s = c.x + c.y + c.z + c.w;
    red[tid] = s;
    __syncthreads();
    for (int d = 1; d < 256; d <<= 1) {
        int t = (tid >= d) ? red[tid - d] : 0;
        __syncthreads();
        red[tid] += t;
        __syncthreads();
    }
    int excl = red[tid] - s + partials[blockIdx.x];
    int4 rp;
    rp.x = excl;
    rp.y = excl + c.x;
    rp.z = excl + c.x + c.y;
    rp.w = excl + c.x + c.y + c.z;
    if (idx + 3 < n) {
        *(int4*)(row_ptr + idx) = rp;
        *(int4*)(cursor + idx) = rp;
    } else {
        if (idx + 0 < n) { row_ptr[idx + 0] = rp.x; cursor[idx + 0] = rp.x; }
        if (idx + 1 < n) { row_ptr[idx + 1] = rp.y; cursor[idx + 1] = rp.y; }
        if (idx + 2 < n) { row_ptr[idx + 2] = rp.z; cursor[idx + 2] = rp.z; }
    }
    if (blockIdx.x == 0 && tid == 0) row_ptr[n] = E;
}

__global__ __launch_bounds__(256) void csr_fill(const int* __restrict__ edge, int E,
                                                int* __restrict__ cursor,
                                                int* __restrict__ col) {
    int i = blockIdx.x * 256 + threadIdx.x;
    if (i >= E) return;
    int dst = edge[i];
    int src = edge[E + i];
    int pos = atomicAdd(&cursor[dst], 1);
    col[pos] = src;
}

// ---------------------------------------------------------------------------
// gather: U[i] = relu( U[i] + sum_{src in adj(i)} T[src] )   (in-place on U)
// one 32-lane group per node; lane owns float4 (4 cols)
// ---------------------------------------------------------------------------
__global__ __launch_bounds__(256) void gather_relu(const float* __restrict__ T,
                                                   const int* __restrict__ row_ptr,
                                                   const int* __restrict__ col,
                                                   float* __restrict__ U, int n) {
    int g = (int)((blockIdx.x * 256u + threadIdx.x) >> 5);
    int lane = threadIdx.x & 31;
    if (g >= n) return;
    int start = row_ptr[g];
    int end = row_ptr[g + 1];
    float4 acc = *(const float4*)(U + (size_t)g * H + lane * 4);
    for (int e0 = start; e0 < end; e0 += 32) {
        int idx = e0 + lane;
        int myc = (idx < end) ? col[idx] : 0;
        int cnt = min(32, end - e0);
        for (int j = 0; j < cnt; ++j) {
            int src = __shfl(myc, j, 32);
            const float4 v = *(const float4*)(T + (size_t)src * H + lane * 4);
            acc.x += v.x; acc.y += v.y; acc.z += v.z; acc.w += v.w;
        }
    }
    acc.x = fmaxf(acc.x, 0.f);
    acc.y = fmaxf(acc.y, 0.f);
    acc.z = fmaxf(acc.z, 0.f);
    acc.w = fmaxf(acc.w, 0.f);
    *(float4*)(U + (size_t)g * H + lane * 4) = acc;
}

// ---------------------------------------------------------------------------
// dual GEMM: T = A@W1 ; U = A@W2 + bias   (rows tiled by 32; safe for U==A)
// ---------------------------------------------------------------------------
__global__ __launch_bounds__(256) void gemm_dual(const float* __restrict__ A,
                                                 const float* __restrict__ W1,
                                                 const float* __restrict__ W2,
                                                 const float* __restrict__ bias,
                                                 float* __restrict__ T,
                                                 float* __restrict__ U, int nrows) {
    __shared__ float As[32][H];
    int row0 = blockIdx.x * 32;
    int tid = threadIdx.x;
    {
        const float4* Ap = (const float4*)(A + (size_t)row0 * H);
        float4* As4 = (float4*)&As[0][0];
        #pragma unroll
        for (int i = 0; i < 4; ++i) As4[tid + 256 * i] = Ap[tid + 256 * i];
    }
    __syncthreads();

    int c4 = tid & 31;
    int rg = tid >> 5;
    float4 bv = *(const float4*)(bias + c4 * 4);
    float4 acc1[4] = {{0,0,0,0},{0,0,0,0},{0,0,0,0},{0,0,0,0}};
    float4 acc2[4] = {bv, bv, bv, bv};

    const float4* W1p = (const float4*)W1;
    const float4* W2p = (const float4*)W2;

    for (int k = 0; k < H; ++k) {
        float4 w1 = W1p[k * 32 + c4];
        float4 w2 = W2p[k * 32 + c4];
        #pragma unroll
        for (int i = 0; i < 4; ++i) {
            float a = As[rg * 4 + i][k];
            acc1[i].x += a * w1.x; acc1[i].y += a * w1.y;
            acc1[i].z += a * w1.z; acc1[i].w += a * w1.w;
            acc2[i].x += a * w2.x; acc2[i].y += a * w2.y;
            acc2[i].z += a * w2.z; acc2[i].w += a * w2.w;
        }
    }

    #pragma unroll
    for (int i = 0; i < 4; ++i) {
        int r = row0 + rg * 4 + i;
        if (r < nrows) {
            *(float4*)(T + (size_t)r * H + c4 * 4) = acc1[i];
            *(float4*)(U + (size_t)r * H + c4 * 4) = acc2[i];
        }
    }
}

// ---------------------------------------------------------------------------
// single GEMM: out = A@W + bias   (no relu)
// ---------------------------------------------------------------------------
__global__ __launch_bounds__(256) void gemm_single(const float* __restrict__ A,
                                                   const float* __restrict__ W,
                                                   const float* __restrict__ bias,
                                                   float* __restrict__ out, int nrows) {
    __shared__ float As[32][H];
    int row0 = blockIdx.x * 32;
    int tid = threadIdx.x;
    {
        const float4* Ap = (const float4*)(A + (size_t)row0 * H);
        float4* As4 = (float4*)&As[0][0];
        #pragma unroll
        for (int i = 0; i < 4; ++i) As4[tid + 256 * i] = Ap[tid + 256 * i];
    }
    __syncthreads();

    int c4 = tid & 31;
    int rg = tid >> 5;
    float4 bv = *(const float4*)(bias + c4 * 4);
    float4 acc[4] = {bv, bv, bv, bv};
    const float4* Wp = (const float4*)W;

    for (int k = 0; k < H; ++k) {
        float4 w = Wp[k * 32 + c4];
        #pragma unroll
        for (int i = 0; i < 4; ++i) {
            float a = As[rg * 4 + i][k];
            acc[i].x += a * w.x; acc[i].y += a * w.y;
            acc[i].z += a * w.z; acc[i].w += a * w.w;
        }
    }
    #pragma unroll
    for (int i = 0; i < 4; ++i) {
        int r = row0 + rg * 4 + i;
        if (r < nrows)
            *(float4*)(out + (size_t)r * H + c4 * 4) = acc[i];
    }
}

extern "C" void kernel_launch(void* const* d_in, const int* in_sizes, int n_in,
                              void* d_out, int out_size, void* d_ws, size_t ws_size,
                              hipStream_t stream) {
    const float* x_A  = (const float*)d_in[0];
    const int* edge_r0 = (const int*)d_in[2];
    const int* edge_r1 = (const int*)d_in[3];
    const float* wl0 = (const float*)d_in[4];
    const float* bl0 = (const float*)d_in[5];
    const float* w00 = (const float*)d_in[6];
    const float* b00 = (const float*)d_in[7];
    const float* w10 = (const float*)d_in[8];
    const float* b10 = (const float*)d_in[9];
    const float* wl1 = (const float*)d_in[10];
    const float* bl1 = (const float*)d_in[11];
    const float* w01 = (const float*)d_in[12];
    const float* b01 = (const float*)d_in[13];
    const float* w11 = (const float*)d_in[14];
    const float* b11 = (const float*)d_in[15];
    const float* w_out = (const float*)d_in[16];
    const float* b_out = (const float*)d_in[17];

    const int N = in_sizes[0] / H;       // 100000
    const int E = in_sizes[2] / 2;       // 1600000

    char* ws = (char*)d_ws;
    float* U        = (float*)ws;                        ws += (size_t)N * H * sizeof(float);
    int*   row_ptr  = (int*)ws;                          ws += (size_t)(N + 1) * sizeof(int);
    int*   cursor   = (int*)ws;                          ws += (size_t)N * sizeof(int);
    int*   counts   = (int*)ws;                          ws += (size_t)N * sizeof(int);
    int*   partials = (int*)ws;                          ws += 256 * sizeof(int);
    int*   colbuf   = (int*)ws;                          ws += (size_t)E * sizeof(int);
    float* wc1      = (float*)ws;                        ws += H * H * sizeof(float);
    float* wc0      = (float*)ws;                        ws += H * H * sizeof(float);
    float* bc1      = (float*)ws;                        ws += H * sizeof(float);
    float* bc0      = (float*)ws;                        ws += H * sizeof(float);
    float* T        = (float*)d_out;  // t-buffer lives in d_out until the end

    prep_weights<<<(H * H + 255) / 256, 256, 0, stream>>>(
        w01, w11, bl1, b01, b11, w00, w10, bl0, b00, b10, wc1, bc1, wc0, bc0);

    const int eBlocks = (E + 255) / 256;
    const int gemmBlocks = (N + 31) / 32;
    const int gatherBlocks = (N * 32 + 255) / 256;
    const int scanBlocks = (N + 1023) / 1024;   // 98

    // ---- layer 1 (edge_r1): t1 = x_A@wl1 -> T ; u1 = x_A@wc1+bc1 -> U ----
    hipMemsetAsync(counts, 0, (size_t)N * sizeof(int), stream);
    csr_hist<<<eBlocks, 256, 0, stream>>>(edge_r1, E, counts);
    csr_blocksum<<<scanBlocks, 256, 0, stream>>>(counts, N, partials);
    csr_scanpart<<<1, 256, 0, stream>>>(partials, scanBlocks);
    csr_writeptr<<<scanBlocks, 256, 0, stream>>>(counts, N, partials, row_ptr, cursor, E);
    csr_fill<<<eBlocks, 256, 0, stream>>>(edge_r1, E, cursor, colbuf);
    gemm_dual<<<gemmBlocks, 256, 0, stream>>>(x_A, wl1, wc1, bc1, T, U, N);
    gather_relu<<<gatherBlocks, 256, 0, stream>>>(T, row_ptr, colbuf, U, N);  // h1 = U

    // ---- layer 2 (edge_r0): t2 = h1@wl0 -> T ; u2 = h1@wc0+bc0 -> U ----
    hipMemsetAsync(counts, 0, (size_t)N * sizeof(int), stream);
    csr_hist<<<eBlocks, 256, 0, stream>>>(edge_r0, E, counts);
    csr_blocksum<<<scanBlocks, 256, 0, stream>>>(counts, N, partials);
    csr_scanpart<<<1, 256, 0, stream>>>(partials, scanBlocks);
    csr_writeptr<<<scanBlocks, 256, 0, stream>>>(counts, N, partials, row_ptr, cursor, E);
    csr_fill<<<eBlocks, 256, 0, stream>>>(edge_r0, E, cursor, colbuf);
    gemm_dual<<<gemmBlocks, 256, 0, stream>>>(U, wl0, wc0, bc0, T, U, N);
    gather_relu<<<gatherBlocks, 256, 0, stream>>>(T, row_ptr, colbuf, U, N);  // h2 = U

    // ---- out = h2 @ w_out + b_out  (reads U, writes d_out; no aliasing) ----
    gemm_single<<<gemmBlocks, 256, 0, stream>>>(U, w_out, b_out, (float*)d_out, N);
}

// Round 4
// 714.397 us; speedup vs baseline: 8.0464x; 1.3951x over previous
//
#include <hip/hip_runtime.h>
#include <hip/hip_bf16.h>

#define H 128

typedef __attribute__((ext_vector_type(8))) short bf16x8;
typedef __attribute__((ext_vector_type(4))) float f32x4;

static __device__ __forceinline__ unsigned short f2bf(float f) {
    unsigned u = __float_as_uint(f);
    u += 0x7FFFu + ((u >> 16) & 1u);          // round-to-nearest-even
    return (unsigned short)(u >> 16);
}
static __device__ __forceinline__ float bflo(unsigned u) {   // low bf16 of a u32
    return __uint_as_float(u << 16);
}
static __device__ __forceinline__ float bfhi(unsigned u) {   // high bf16 of a u32
    return __uint_as_float(u & 0xFFFF0000u);
}

// ---------------------------------------------------------------------------
// prep: transposed bf16 weights  Wt[c][k] = bf16(W[k][c])  (+ combined wc, bc)
// ---------------------------------------------------------------------------
__global__ __launch_bounds__(256) void prep_weights_t(
        const float* __restrict__ wl1, const float* __restrict__ w01,
        const float* __restrict__ w11, const float* __restrict__ bl1,
        const float* __restrict__ b01, const float* __restrict__ b11,
        const float* __restrict__ wl0, const float* __restrict__ w00,
        const float* __restrict__ w10, const float* __restrict__ bl0,
        const float* __restrict__ b00, const float* __restrict__ b10,
        const float* __restrict__ w_out,
        unsigned short* __restrict__ Wt_l1, unsigned short* __restrict__ Wt_c1,
        unsigned short* __restrict__ Wt_l0, unsigned short* __restrict__ Wt_c0,
        unsigned short* __restrict__ Wt_o,
        float* __restrict__ bc1, float* __restrict__ bc0) {
    int i = blockIdx.x * 256 + threadIdx.x;     // i = k*H + c
    if (i < H * H) {
        int k = i >> 7, c = i & (H - 1);
        int t = c * H + k;
        Wt_l1[t] = f2bf(wl1[i]);
        Wt_c1[t] = f2bf(w01[i] + w11[i]);
        Wt_l0[t] = f2bf(wl0[i]);
        Wt_c0[t] = f2bf(w00[i] + w10[i]);
        Wt_o[t]  = f2bf(w_out[i]);
        if (i < H) {
            bc1[i] = bl1[i] + b01[i] + b11[i];
            bc0[i] = bl0[i] + b00[i] + b10[i];
        }
    }
}

// ---------------------------------------------------------------------------
// CSR build: histogram -> hierarchical scan -> fill
// ---------------------------------------------------------------------------
__global__ __launch_bounds__(256) void csr_hist(const int* __restrict__ edge, int E,
                                                int* __restrict__ counts) {
    int i = blockIdx.x * 256 + threadIdx.x;
    if (i < E) atomicAdd(&counts[edge[i]], 1);
}

__global__ __launch_bounds__(256) void csr_blocksum(const int* __restrict__ counts, int n,
                                                    int* __restrict__ partials) {
    __shared__ int red[256];
    int tid = threadIdx.x;
    int idx = blockIdx.x * 1024 + tid * 4;
    int s = 0;
    if (idx + 3 < n) {
        int4 c = *(const int4*)(counts + idx);
        s = c.x + c.y + c.z + c.w;
    } else {
        for (int j = 0; j < 4; ++j)
            if (idx + j < n) s += counts[idx + j];
    }
    red[tid] = s;
    __syncthreads();
    for (int d = 128; d > 0; d >>= 1) {
        if (tid < d) red[tid] += red[tid + d];
        __syncthreads();
    }
    if (tid == 0) partials[blockIdx.x] = red[0];
}

__global__ __launch_bounds__(256) void csr_scanpart(int* __restrict__ partials, int nb) {
    __shared__ int buf[256];
    int tid = threadIdx.x;
    int v = (tid < nb) ? partials[tid] : 0;
    buf[tid] = v;
    __syncthreads();
    for (int d = 1; d < 256; d <<= 1) {
        int t = (tid >= d) ? buf[tid - d] : 0;
        __syncthreads();
        buf[tid] += t;
        __syncthreads();
    }
    if (tid < nb) partials[tid] = buf[tid] - v;
}

__global__ __launch_bounds__(256) void csr_writeptr(const int* __restrict__ counts, int n,
                                                    const int* __restrict__ partials,
                                                    int* __restrict__ row_ptr,
                                                    int* __restrict__ cursor, int E) {
    __shared__ int red[256];
    int tid = threadIdx.x;
    int idx = blockIdx.x * 1024 + tid * 4;
    int4 c = {0, 0, 0, 0};
    if (idx + 3 < n) {
        c = *(const int4*)(counts + idx);
    } else {
        if (idx + 0 < n) c.x = counts[idx + 0];
        if (idx + 1 < n) c.y = counts[idx + 1];
        if (idx + 2 < n) c.z = counts[idx + 2];
    }
    int s = c.x + c.y + c.z + c.w;
    red[tid] = s;
    __syncthreads();
    for (int d = 1; d < 256; d <<= 1) {
        int t = (tid >= d) ? red[tid - d] : 0;
        __syncthreads();
        red[tid] += t;
        __syncthreads();
    }
    int excl = red[tid] - s + partials[blockIdx.x];
    int4 rp;
    rp.x = excl;
    rp.y = excl + c.x;
    rp.z = excl + c.x + c.y;
    rp.w = excl + c.x + c.y + c.z;
    if (idx + 3 < n) {
        *(int4*)(row_ptr + idx) = rp;
        *(int4*)(cursor + idx) = rp;
    } else {
        if (idx + 0 < n) { row_ptr[idx + 0] = rp.x; cursor[idx + 0] = rp.x; }
        if (idx + 1 < n) { row_ptr[idx + 1] = rp.y; cursor[idx + 1] = rp.y; }
        if (idx + 2 < n) { row_ptr[idx + 2] = rp.z; cursor[idx + 2] = rp.z; }
    }
    if (blockIdx.x == 0 && tid == 0) row_ptr[n] = E;
}

__global__ __launch_bounds__(256) void csr_fill(const int* __restrict__ edge, int E,
                                                int* __restrict__ cursor,
                                                int* __restrict__ col) {
    int i = blockIdx.x * 256 + threadIdx.x;
    if (i >= E) return;
    int dst = edge[i];
    int src = edge[E + i];
    int pos = atomicAdd(&cursor[dst], 1);
    col[pos] = src;
}

// ---------------------------------------------------------------------------
// dual MFMA GEMM:  T(bf16) = A@W1 ; U(f32) = A@W2 + bias
// A fp32 [M][128]; Wt* transposed bf16 [c][k]. 4 waves/block, 16 rows/wave.
// Safe for U == A (each wave writes only its own rows, after all its reads).
// ---------------------------------------------------------------------------
__global__ __launch_bounds__(256) void gemm_dual_mfma(
        const float* __restrict__ A,
        const unsigned short* __restrict__ Wt1,
        const unsigned short* __restrict__ Wt2,
        const float* __restrict__ bias,
        unsigned short* __restrict__ T,
        float* __restrict__ U, int M) {
    int tid = threadIdx.x;
    int wave = tid >> 6;
    int lane = tid & 63;
    int r0 = blockIdx.x * 64 + wave * 16;
    int lrow = lane & 15;
    int koff = (lane >> 4) * 8;

    f32x4 accT[8] = {};
    f32x4 accU[8] = {};

    int arow = r0 + lrow;
    if (arow >= M) arow = M - 1;              // clamp reads; stores are guarded
    const float* Arow = A + (size_t)arow * H;

    for (int kt = 0; kt < 4; ++kt) {
        int k = kt * 32 + koff;
        float4 a0 = *(const float4*)(Arow + k);
        float4 a1 = *(const float4*)(Arow + k + 4);
        bf16x8 af;
        af[0] = (short)f2bf(a0.x); af[1] = (short)f2bf(a0.y);
        af[2] = (short)f2bf(a0.z); af[3] = (short)f2bf(a0.w);
        af[4] = (short)f2bf(a1.x); af[5] = (short)f2bf(a1.y);
        af[6] = (short)f2bf(a1.z); af[7] = (short)f2bf(a1.w);
        #pragma unroll
        for (int nt = 0; nt < 8; ++nt) {
            int c = nt * 16 + lrow;
            bf16x8 b1 = *(const bf16x8*)(Wt1 + (size_t)c * H + k);
            bf16x8 b2 = *(const bf16x8*)(Wt2 + (size_t)c * H + k);
            accT[nt] = __builtin_amdgcn_mfma_f32_16x16x32_bf16(af, b1, accT[nt], 0, 0, 0);
            accU[nt] = __builtin_amdgcn_mfma_f32_16x16x32_bf16(af, b2, accU[nt], 0, 0, 0);
        }
    }

    int orow = r0 + (lane >> 4) * 4;          // C/D: col=lane&15, row=(lane>>4)*4+reg
    #pragma unroll
    for (int nt = 0; nt < 8; ++nt) {
        int c = nt * 16 + lrow;
        float bv = bias[c];
        #pragma unroll
        for (int i = 0; i < 4; ++i) {
            int r = orow + i;
            if (r < M) {
                T[(size_t)r * H + c] = f2bf(accT[nt][i]);
                U[(size_t)r * H + c] = accU[nt][i] + bv;
            }
        }
    }
}

// ---------------------------------------------------------------------------
// single MFMA GEMM:  out(f32) = A@W + bias
// ---------------------------------------------------------------------------
__global__ __launch_bounds__(256) void gemm_single_mfma(
        const float* __restrict__ A,
        const unsigned short* __restrict__ Wt,
        const float* __restrict__ bias,
        float* __restrict__ out, int M) {
    int tid = threadIdx.x;
    int wave = tid >> 6;
    int lane = tid & 63;
    int r0 = blockIdx.x * 64 + wave * 16;
    int lrow = lane & 15;
    int koff = (lane >> 4) * 8;

    f32x4 acc[8] = {};

    int arow = r0 + lrow;
    if (arow >= M) arow = M - 1;
    const float* Arow = A + (size_t)arow * H;

    for (int kt = 0; kt < 4; ++kt) {
        int k = kt * 32 + koff;
        float4 a0 = *(const float4*)(Arow + k);
        float4 a1 = *(const float4*)(Arow + k + 4);
        bf16x8 af;
        af[0] = (short)f2bf(a0.x); af[1] = (short)f2bf(a0.y);
        af[2] = (short)f2bf(a0.z); af[3] = (short)f2bf(a0.w);
        af[4] = (short)f2bf(a1.x); af[5] = (short)f2bf(a1.y);
        af[6] = (short)f2bf(a1.z); af[7] = (short)f2bf(a1.w);
        #pragma unroll
        for (int nt = 0; nt < 8; ++nt) {
            int c = nt * 16 + lrow;
            bf16x8 b = *(const bf16x8*)(Wt + (size_t)c * H + k);
            acc[nt] = __builtin_amdgcn_mfma_f32_16x16x32_bf16(af, b, acc[nt], 0, 0, 0);
        }
    }

    int orow = r0 + (lane >> 4) * 4;
    #pragma unroll
    for (int nt = 0; nt < 8; ++nt) {
        int c = nt * 16 + lrow;
        float bv = bias[c];
        #pragma unroll
        for (int i = 0; i < 4; ++i) {
            int r = orow + i;
            if (r < M)
                out[(size_t)r * H + c] = acc[nt][i] + bv;
        }
    }
}

// ---------------------------------------------------------------------------
// gather: U[i] = relu( U[i] + sum_{src in adj(i)} T[src] )   (T bf16, U f32)
// 16-lane group per node; lane owns 8 cols (one uint4 = 8 bf16 per row read)
// ---------------------------------------------------------------------------
__global__ __launch_bounds__(256) void gather_relu_bf16(
        const unsigned short* __restrict__ T,
        const int* __restrict__ row_ptr,
        const int* __restrict__ col,
        float* __restrict__ U, int n) {
    int g = (int)((blockIdx.x * 256u + threadIdx.x) >> 4);
    int lane = threadIdx.x & 15;
    if (g >= n) return;
    int start = row_ptr[g];
    int end = row_ptr[g + 1];
    float* Urow = U + (size_t)g * H + lane * 8;
    float4 acc0 = *(const float4*)(Urow);
    float4 acc1 = *(const float4*)(Urow + 4);
    for (int e0 = start; e0 < end; e0 += 16) {
        int idx = e0 + lane;
        int myc = (idx < end) ? col[idx] : 0;
        int cnt = min(16, end - e0);
        for (int j = 0; j < cnt; ++j) {
            int src = __shfl(myc, j, 16);
            uint4 v = *(const uint4*)(T + (size_t)src * H + lane * 8);
            acc0.x += bflo(v.x); acc0.y += bfhi(v.x);
            acc0.z += bflo(v.y); acc0.w += bfhi(v.y);
            acc1.x += bflo(v.z); acc1.y += bfhi(v.z);
            acc1.z += bflo(v.w); acc1.w += bfhi(v.w);
        }
    }
    acc0.x = fmaxf(acc0.x, 0.f); acc0.y = fmaxf(acc0.y, 0.f);
    acc0.z = fmaxf(acc0.z, 0.f); acc0.w = fmaxf(acc0.w, 0.f);
    acc1.x = fmaxf(acc1.x, 0.f); acc1.y = fmaxf(acc1.y, 0.f);
    acc1.z = fmaxf(acc1.z, 0.f); acc1.w = fmaxf(acc1.w, 0.f);
    *(float4*)(Urow) = acc0;
    *(float4*)(Urow + 4) = acc1;
}

extern "C" void kernel_launch(void* const* d_in, const int* in_sizes, int n_in,
                              void* d_out, int out_size, void* d_ws, size_t ws_size,
                              hipStream_t stream) {
    const float* x_A  = (const float*)d_in[0];
    const int* edge_r0 = (const int*)d_in[2];
    const int* edge_r1 = (const int*)d_in[3];
    const float* wl0 = (const float*)d_in[4];
    const float* bl0 = (const float*)d_in[5];
    const float* w00 = (const float*)d_in[6];
    const float* b00 = (const float*)d_in[7];
    const float* w10 = (const float*)d_in[8];
    const float* b10 = (const float*)d_in[9];
    const float* wl1 = (const float*)d_in[10];
    const float* bl1 = (const float*)d_in[11];
    const float* w01 = (const float*)d_in[12];
    const float* b01 = (const float*)d_in[13];
    const float* w11 = (const float*)d_in[14];
    const float* b11 = (const float*)d_in[15];
    const float* w_out = (const float*)d_in[16];
    const float* b_out = (const float*)d_in[17];

    const int N = in_sizes[0] / H;       // 100000
    const int E = in_sizes[2] / 2;       // 1600000

    char* ws = (char*)d_ws;
    float* U        = (float*)ws;                        ws += (size_t)N * H * sizeof(float);
    int*   row_ptr  = (int*)ws;                          ws += (size_t)(N + 1) * sizeof(int);
    int*   cursor   = (int*)ws;                          ws += (size_t)N * sizeof(int);
    int*   counts   = (int*)ws;                          ws += (size_t)N * sizeof(int);
    int*   partials = (int*)ws;                          ws += 256 * sizeof(int);
    int*   colbuf   = (int*)ws;                          ws += (size_t)E * sizeof(int);
    unsigned short* Wt_l1 = (unsigned short*)ws;         ws += H * H * sizeof(short);
    unsigned short* Wt_c1 = (unsigned short*)ws;         ws += H * H * sizeof(short);
    unsigned short* Wt_l0 = (unsigned short*)ws;         ws += H * H * sizeof(short);
    unsigned short* Wt_c0 = (unsigned short*)ws;         ws += H * H * sizeof(short);
    unsigned short* Wt_o  = (unsigned short*)ws;         ws += H * H * sizeof(short);
    float* bc1      = (float*)ws;                        ws += H * sizeof(float);
    float* bc0      = (float*)ws;                        ws += H * sizeof(float);
    unsigned short* T = (unsigned short*)d_out;  // bf16 T lives in d_out until the end

    prep_weights_t<<<(H * H + 255) / 256, 256, 0, stream>>>(
        wl1, w01, w11, bl1, b01, b11, wl0, w00, w10, bl0, b00, b10, w_out,
        Wt_l1, Wt_c1, Wt_l0, Wt_c0, Wt_o, bc1, bc0);

    const int eBlocks = (E + 255) / 256;
    const int gemmBlocks = (N + 63) / 64;
    const int gatherBlocks = (N * 16 + 255) / 256;
    const int scanBlocks = (N + 1023) / 1024;

    // ---- layer 1 (edge_r1): T = bf16(x_A@wl1) ; U = x_A@wc1 + bc1 ----
    hipMemsetAsync(counts, 0, (size_t)N * sizeof(int), stream);
    csr_hist<<<eBlocks, 256, 0, stream>>>(edge_r1, E, counts);
    csr_blocksum<<<scanBlocks, 256, 0, stream>>>(counts, N, partials);
    csr_scanpart<<<1, 256, 0, stream>>>(partials, scanBlocks);
    csr_writeptr<<<scanBlocks, 256, 0, stream>>>(counts, N, partials, row_ptr, cursor, E);
    csr_fill<<<eBlocks, 256, 0, stream>>>(edge_r1, E, cursor, colbuf);
    gemm_dual_mfma<<<gemmBlocks, 256, 0, stream>>>(x_A, Wt_l1, Wt_c1, bc1, T, U, N);
    gather_relu_bf16<<<gatherBlocks, 256, 0, stream>>>(T, row_ptr, colbuf, U, N);  // h1 = U

    // ---- layer 2 (edge_r0): T = bf16(h1@wl0) ; U = h1@wc0 + bc0 (in-place) ----
    hipMemsetAsync(counts, 0, (size_t)N * sizeof(int), stream);
    csr_hist<<<eBlocks, 256, 0, stream>>>(edge_r0, E, counts);
    csr_blocksum<<<scanBlocks, 256, 0, stream>>>(counts, N, partials);
    csr_scanpart<<<1, 256, 0, stream>>>(partials, scanBlocks);
    csr_writeptr<<<scanBlocks, 256, 0, stream>>>(counts, N, partials, row_ptr, cursor, E);
    csr_fill<<<eBlocks, 256, 0, stream>>>(edge_r0, E, cursor, colbuf);
    gemm_dual_mfma<<<gemmBlocks, 256, 0, stream>>>(U, Wt_l0, Wt_c0, bc0, T, U, N);
    gather_relu_bf16<<<gatherBlocks, 256, 0, stream>>>(T, row_ptr, colbuf, U, N);  // h2 = U

    // ---- out = h2 @ w_out + b_out  (reads U, overwrites d_out; T is dead) ----
    gemm_single_mfma<<<gemmBlocks, 256, 0, stream>>>(U, Wt_o, b_out, (float*)d_out, N);
}

// Round 5
// 411.162 us; speedup vs baseline: 13.9808x; 1.7375x over previous
//
#include <hip/hip_runtime.h>
#include <hip/hip_bf16.h>

#define H 128
#define BPAD 4608            // padded per-bucket capacity (mean 4096, ~8 sigma)
#define EPB 4096             // edges per scatter block

typedef __attribute__((ext_vector_type(8))) short bf16x8;
typedef __attribute__((ext_vector_type(4))) float f32x4;

static __device__ __forceinline__ unsigned short f2bf(float f) {
    unsigned u = __float_as_uint(f);
    u += 0x7FFFu + ((u >> 16) & 1u);          // round-to-nearest-even
    return (unsigned short)(u >> 16);
}
static __device__ __forceinline__ float bflo(unsigned u) {
    return __uint_as_float(u << 16);
}
static __device__ __forceinline__ float bfhi(unsigned u) {
    return __uint_as_float(u & 0xFFFF0000u);
}

// ---------------------------------------------------------------------------
// prep: transposed bf16 weights  Wt[c][k] = bf16(W[k][c])  (+ combined wc, bc)
// ---------------------------------------------------------------------------
__global__ __launch_bounds__(256) void prep_weights_t(
        const float* __restrict__ wl1, const float* __restrict__ w01,
        const float* __restrict__ w11, const float* __restrict__ bl1,
        const float* __restrict__ b01, const float* __restrict__ b11,
        const float* __restrict__ wl0, const float* __restrict__ w00,
        const float* __restrict__ w10, const float* __restrict__ bl0,
        const float* __restrict__ b00, const float* __restrict__ b10,
        const float* __restrict__ w_out,
        unsigned short* __restrict__ Wt_l1, unsigned short* __restrict__ Wt_c1,
        unsigned short* __restrict__ Wt_l0, unsigned short* __restrict__ Wt_c0,
        unsigned short* __restrict__ Wt_o,
        float* __restrict__ bc1, float* __restrict__ bc0) {
    int i = blockIdx.x * 256 + threadIdx.x;     // i = k*H + c
    if (i < H * H) {
        int k = i >> 7, c = i & (H - 1);
        int t = c * H + k;
        Wt_l1[t] = f2bf(wl1[i]);
        Wt_c1[t] = f2bf(w01[i] + w11[i]);
        Wt_l0[t] = f2bf(wl0[i]);
        Wt_c0[t] = f2bf(w00[i] + w10[i]);
        Wt_o[t]  = f2bf(w_out[i]);
        if (i < H) {
            bc1[i] = bl1[i] + b01[i] + b11[i];
            bc0[i] = bl0[i] + b00[i] + b10[i];
        }
    }
}

// ---------------------------------------------------------------------------
// CSR phase 1: coarse-bucket scatter.  bucket = dst>>8 (256 nodes/bucket).
// Per-block LDS histogram -> one global atomicAdd per (block,bucket) to
// reserve a chunk -> LDS-cursor scatter of packed (src<<8 | dst&255).
// ---------------------------------------------------------------------------
__global__ __launch_bounds__(256) void bucket_scatter(const int* __restrict__ edge, int E,
                                                      int* __restrict__ gcur,
                                                      int* __restrict__ packed) {
    __shared__ int lhist[512];
    __shared__ int lcur[512];
    int tid = threadIdx.x;
    lhist[tid] = 0;
    lhist[tid + 256] = 0;
    __syncthreads();

    int e0 = blockIdx.x * EPB;
    int d[16], s[16];
    #pragma unroll
    for (int j = 0; j < 16; ++j) {
        int e = e0 + j * 256 + tid;
        bool v = (e < E);
        d[j] = v ? edge[e] : -1;
        s[j] = v ? edge[E + e] : 0;
        if (v) atomicAdd(&lhist[d[j] >> 8], 1);
    }
    __syncthreads();

    for (int i = tid; i < 512; i += 256) {
        int c = lhist[i];
        lcur[i] = (c > 0) ? atomicAdd(&gcur[i], c) : 0;
    }
    __syncthreads();

    #pragma unroll
    for (int j = 0; j < 16; ++j) {
        if (d[j] >= 0) {
            int b = d[j] >> 8;
            int p = atomicAdd(&lcur[b], 1);
            if (p < BPAD)
                packed[(size_t)b * BPAD + p] = (s[j] << 8) | (d[j] & 255);
        }
    }
}

// ---------------------------------------------------------------------------
// CSR phase 2: per-bucket fine build.  LDS 256-bin hist + scan ->
// nodeinfo[node] = (start, count), col positions via LDS atomics.
// ---------------------------------------------------------------------------
__global__ __launch_bounds__(256) void bucket_build(const int* __restrict__ gcur,
                                                    const int* __restrict__ packed,
                                                    int* __restrict__ col,
                                                    int2* __restrict__ nodeinfo, int n) {
    __shared__ int hist[256];
    __shared__ int off[256];
    int b = blockIdx.x;
    int tid = threadIdx.x;
    int L = gcur[b];
    if (L > BPAD) L = BPAD;
    hist[tid] = 0;
    __syncthreads();

    const int* base = packed + (size_t)b * BPAD;
    for (int i = tid; i < L; i += 256)
        atomicAdd(&hist[base[i] & 255], 1);
    __syncthreads();

    int v = hist[tid];
    off[tid] = v;
    __syncthreads();
    for (int dd = 1; dd < 256; dd <<= 1) {
        int t = (tid >= dd) ? off[tid - dd] : 0;
        __syncthreads();
        off[tid] += t;
        __syncthreads();
    }
    int excl = off[tid] - v;

    int node = b * 256 + tid;
    if (node < n)
        nodeinfo[node] = make_int2(b * BPAD + excl, v);

    hist[tid] = excl;           // reuse as cursor
    __syncthreads();
    for (int i = tid; i < L; i += 256) {
        int pk = base[i];
        int p = atomicAdd(&hist[pk & 255], 1);
        col[(size_t)b * BPAD + p] = pk >> 8;
    }
}

// ---------------------------------------------------------------------------
// dual MFMA GEMM:  T(bf16) = A@W1 ; U(f32) = A@W2 + bias
// ---------------------------------------------------------------------------
__global__ __launch_bounds__(256) void gemm_dual_mfma(
        const float* __restrict__ A,
        const unsigned short* __restrict__ Wt1,
        const unsigned short* __restrict__ Wt2,
        const float* __restrict__ bias,
        unsigned short* __restrict__ T,
        float* __restrict__ U, int M) {
    int tid = threadIdx.x;
    int wave = tid >> 6;
    int lane = tid & 63;
    int r0 = blockIdx.x * 64 + wave * 16;
    int lrow = lane & 15;
    int koff = (lane >> 4) * 8;

    f32x4 accT[8] = {};
    f32x4 accU[8] = {};

    int arow = r0 + lrow;
    if (arow >= M) arow = M - 1;
    const float* Arow = A + (size_t)arow * H;

    for (int kt = 0; kt < 4; ++kt) {
        int k = kt * 32 + koff;
        float4 a0 = *(const float4*)(Arow + k);
        float4 a1 = *(const float4*)(Arow + k + 4);
        bf16x8 af;
        af[0] = (short)f2bf(a0.x); af[1] = (short)f2bf(a0.y);
        af[2] = (short)f2bf(a0.z); af[3] = (short)f2bf(a0.w);
        af[4] = (short)f2bf(a1.x); af[5] = (short)f2bf(a1.y);
        af[6] = (short)f2bf(a1.z); af[7] = (short)f2bf(a1.w);
        #pragma unroll
        for (int nt = 0; nt < 8; ++nt) {
            int c = nt * 16 + lrow;
            bf16x8 b1 = *(const bf16x8*)(Wt1 + (size_t)c * H + k);
            bf16x8 b2 = *(const bf16x8*)(Wt2 + (size_t)c * H + k);
            accT[nt] = __builtin_amdgcn_mfma_f32_16x16x32_bf16(af, b1, accT[nt], 0, 0, 0);
            accU[nt] = __builtin_amdgcn_mfma_f32_16x16x32_bf16(af, b2, accU[nt], 0, 0, 0);
        }
    }

    int orow = r0 + (lane >> 4) * 4;
    #pragma unroll
    for (int nt = 0; nt < 8; ++nt) {
        int c = nt * 16 + lrow;
        float bv = bias[c];
        #pragma unroll
        for (int i = 0; i < 4; ++i) {
            int r = orow + i;
            if (r < M) {
                T[(size_t)r * H + c] = f2bf(accT[nt][i]);
                U[(size_t)r * H + c] = accU[nt][i] + bv;
            }
        }
    }
}

// ---------------------------------------------------------------------------
// single MFMA GEMM:  out(f32) = A@W + bias
// ---------------------------------------------------------------------------
__global__ __launch_bounds__(256) void gemm_single_mfma(
        const float* __restrict__ A,
        const unsigned short* __restrict__ Wt,
        const float* __restrict__ bias,
        float* __restrict__ out, int M) {
    int tid = threadIdx.x;
    int wave = tid >> 6;
    int lane = tid & 63;
    int r0 = blockIdx.x * 64 + wave * 16;
    int lrow = lane & 15;
    int koff = (lane >> 4) * 8;

    f32x4 acc[8] = {};

    int arow = r0 + lrow;
    if (arow >= M) arow = M - 1;
    const float* Arow = A + (size_t)arow * H;

    for (int kt = 0; kt < 4; ++kt) {
        int k = kt * 32 + koff;
        float4 a0 = *(const float4*)(Arow + k);
        float4 a1 = *(const float4*)(Arow + k + 4);
        bf16x8 af;
        af[0] = (short)f2bf(a0.x); af[1] = (short)f2bf(a0.y);
        af[2] = (short)f2bf(a0.z); af[3] = (short)f2bf(a0.w);
        af[4] = (short)f2bf(a1.x); af[5] = (short)f2bf(a1.y);
        af[6] = (short)f2bf(a1.z); af[7] = (short)f2bf(a1.w);
        #pragma unroll
        for (int nt = 0; nt < 8; ++nt) {
            int c = nt * 16 + lrow;
            bf16x8 b = *(const bf16x8*)(Wt + (size_t)c * H + k);
            acc[nt] = __builtin_amdgcn_mfma_f32_16x16x32_bf16(af, b, acc[nt], 0, 0, 0);
        }
    }

    int orow = r0 + (lane >> 4) * 4;
    #pragma unroll
    for (int nt = 0; nt < 8; ++nt) {
        int c = nt * 16 + lrow;
        float bv = bias[c];
        #pragma unroll
        for (int i = 0; i < 4; ++i) {
            int r = orow + i;
            if (r < M)
                out[(size_t)r * H + c] = acc[nt][i] + bv;
        }
    }
}

// ---------------------------------------------------------------------------
// gather: U[i] = relu( U[i] + sum_{src in adj(i)} T[src] )   (T bf16, U f32)
// ---------------------------------------------------------------------------
__global__ __launch_bounds__(256) void gather_relu_bf16(
        const unsigned short* __restrict__ T,
        const int2* __restrict__ nodeinfo,
        const int* __restrict__ col,
        float* __restrict__ U, int n) {
    int g = (int)((blockIdx.x * 256u + threadIdx.x) >> 4);
    int lane = threadIdx.x & 15;
    if (g >= n) return;
    int2 info = nodeinfo[g];
    int start = info.x;
    int end = info.x + info.y;
    float* Urow = U + (size_t)g * H + lane * 8;
    float4 acc0 = *(const float4*)(Urow);
    float4 acc1 = *(const float4*)(Urow + 4);
    for (int e0 = start; e0 < end; e0 += 16) {
        int idx = e0 + lane;
        int myc = (idx < end) ? col[idx] : 0;
        int cnt = min(16, end - e0);
        for (int j = 0; j < cnt; ++j) {
            int src = __shfl(myc, j, 16);
            uint4 v = *(const uint4*)(T + (size_t)src * H + lane * 8);
            acc0.x += bflo(v.x); acc0.y += bfhi(v.x);
            acc0.z += bflo(v.y); acc0.w += bfhi(v.y);
            acc1.x += bflo(v.z); acc1.y += bfhi(v.z);
            acc1.z += bflo(v.w); acc1.w += bfhi(v.w);
        }
    }
    acc0.x = fmaxf(acc0.x, 0.f); acc0.y = fmaxf(acc0.y, 0.f);
    acc0.z = fmaxf(acc0.z, 0.f); acc0.w = fmaxf(acc0.w, 0.f);
    acc1.x = fmaxf(acc1.x, 0.f); acc1.y = fmaxf(acc1.y, 0.f);
    acc1.z = fmaxf(acc1.z, 0.f); acc1.w = fmaxf(acc1.w, 0.f);
    *(float4*)(Urow) = acc0;
    *(float4*)(Urow + 4) = acc1;
}

extern "C" void kernel_launch(void* const* d_in, const int* in_sizes, int n_in,
                              void* d_out, int out_size, void* d_ws, size_t ws_size,
                              hipStream_t stream) {
    const float* x_A  = (const float*)d_in[0];
    const int* edge_r0 = (const int*)d_in[2];
    const int* edge_r1 = (const int*)d_in[3];
    const float* wl0 = (const float*)d_in[4];
    const float* bl0 = (const float*)d_in[5];
    const float* w00 = (const float*)d_in[6];
    const float* b00 = (const float*)d_in[7];
    const float* w10 = (const float*)d_in[8];
    const float* b10 = (const float*)d_in[9];
    const float* wl1 = (const float*)d_in[10];
    const float* bl1 = (const float*)d_in[11];
    const float* w01 = (const float*)d_in[12];
    const float* b01 = (const float*)d_in[13];
    const float* w11 = (const float*)d_in[14];
    const float* b11 = (const float*)d_in[15];
    const float* w_out = (const float*)d_in[16];
    const float* b_out = (const float*)d_in[17];

    const int N  = in_sizes[0] / H;       // 100000
    const int E1 = in_sizes[3] / 2;       // edges of relation r1
    const int E0 = in_sizes[2] / 2;       // edges of relation r0
    const int NB = (N + 255) / 256;       // 391 coarse buckets

    char* ws = (char*)d_ws;
    float* U          = (float*)ws;                      ws += (size_t)N * H * sizeof(float);
    int*   col        = (int*)ws;                        ws += (size_t)NB * BPAD * sizeof(int);
    int2*  nodeinfo   = (int2*)ws;                       ws += (size_t)N * sizeof(int2);
    int*   gcur       = (int*)ws;                        ws += 512 * sizeof(int);
    unsigned short* Wt_l1 = (unsigned short*)ws;         ws += H * H * sizeof(short);
    unsigned short* Wt_c1 = (unsigned short*)ws;         ws += H * H * sizeof(short);
    unsigned short* Wt_l0 = (unsigned short*)ws;         ws += H * H * sizeof(short);
    unsigned short* Wt_c0 = (unsigned short*)ws;         ws += H * H * sizeof(short);
    unsigned short* Wt_o  = (unsigned short*)ws;         ws += H * H * sizeof(short);
    float* bc1        = (float*)ws;                      ws += H * sizeof(float);
    float* bc0        = (float*)ws;                      ws += H * sizeof(float);

    // T (bf16, 25.6 MB) and packed (7.2 MB) both live inside d_out (51.2 MB);
    // the final gemm_single_mfma overwrites all of d_out.
    unsigned short* T = (unsigned short*)d_out;
    int* packed = (int*)((char*)d_out + (size_t)N * H * sizeof(unsigned short));

    prep_weights_t<<<(H * H + 255) / 256, 256, 0, stream>>>(
        wl1, w01, w11, bl1, b01, b11, wl0, w00, w10, bl0, b00, b10, w_out,
        Wt_l1, Wt_c1, Wt_l0, Wt_c0, Wt_o, bc1, bc0);

    const int gemmBlocks = (N + 63) / 64;
    const int gatherBlocks = (N * 16 + 255) / 256;

    // ---- layer 1 (edge_r1): T = bf16(x_A@wl1) ; U = x_A@wc1 + bc1 ----
    hipMemsetAsync(gcur, 0, 512 * sizeof(int), stream);
    bucket_scatter<<<(E1 + EPB - 1) / EPB, 256, 0, stream>>>(edge_r1, E1, gcur, packed);
    bucket_build<<<NB, 256, 0, stream>>>(gcur, packed, col, nodeinfo, N);
    gemm_dual_mfma<<<gemmBlocks, 256, 0, stream>>>(x_A, Wt_l1, Wt_c1, bc1, T, U, N);
    gather_relu_bf16<<<gatherBlocks, 256, 0, stream>>>(T, nodeinfo, col, U, N);  // h1 = U

    // ---- layer 2 (edge_r0): T = bf16(h1@wl0) ; U = h1@wc0 + bc0 (in-place) ----
    hipMemsetAsync(gcur, 0, 512 * sizeof(int), stream);
    bucket_scatter<<<(E0 + EPB - 1) / EPB, 256, 0, stream>>>(edge_r0, E0, gcur, packed);
    bucket_build<<<NB, 256, 0, stream>>>(gcur, packed, col, nodeinfo, N);
    gemm_dual_mfma<<<gemmBlocks, 256, 0, stream>>>(U, Wt_l0, Wt_c0, bc0, T, U, N);
    gather_relu_bf16<<<gatherBlocks, 256, 0, stream>>>(T, nodeinfo, col, U, N);  // h2 = U

    // ---- out = h2 @ w_out + b_out  (reads U, overwrites all of d_out) ----
    gemm_single_mfma<<<gemmBlocks, 256, 0, stream>>>(U, Wt_o, b_out, (float*)d_out, N);
}